// Round 4
// baseline (213.253 us; speedup 1.0000x reference)
//
#include <hip/hip_runtime.h>
#include <math.h>

// Problem constants: B=1, T=256, D=512, M=64, H=8, HD=64, IN=256, HID=256
#define T_ 256
#define D_ 512
#define M_ 64
#define H_ 8
#define HD_ 64
#define HID_ 256

__device__ __forceinline__ ushort f2bf(float f) {
    union { float f; unsigned u; } x; x.f = f;
    unsigned r = x.u + 0x7FFF + ((x.u >> 16) & 1);
    return (ushort)(r >> 16);
}
__device__ __forceinline__ float bf2f(ushort u) {
    union { unsigned u; float f; } x; x.u = ((unsigned)u) << 16; return x.f;
}

// ---------------------------------------------------------------------------
// prep: transpose 6 512x512 weights to bf16: wT[z][c][k] = W_z[k][c]
// Grid (16, 16, 6) x 256.
// ---------------------------------------------------------------------------
__global__ __launch_bounds__(256) void prep_kernel(
    const float* __restrict__ Wq, const float* __restrict__ Wk,
    const float* __restrict__ Wv, const float* __restrict__ W3,
    const float* __restrict__ W4, const float* __restrict__ Wo,
    ushort* __restrict__ wT)
{
    const int z = blockIdx.z;
    const float* src = (z == 0) ? Wq : (z == 1) ? Wk : (z == 2) ? Wv
                     : (z == 3) ? W3 : (z == 4) ? W4 : Wo;
    ushort* dst = wT + (long)z * (D_ * D_);
    __shared__ ushort tile[32][33];
    const int k0 = blockIdx.y * 32, c0 = blockIdx.x * 32;
    const int t = threadIdx.x;
    #pragma unroll
    for (int l = 0; l < 4; ++l) {
        int idx = t + l * 256; int r = idx >> 5, c = idx & 31;
        tile[r][c] = f2bf(src[(long)(k0 + r) * D_ + c0 + c]);
    }
    __syncthreads();
    #pragma unroll
    for (int l = 0; l < 4; ++l) {
        int idx = t + l * 256; int r = idx >> 5, c = idx & 31;
        dst[(long)(c0 + r) * D_ + k0 + c] = tile[c][r];
    }
}

// ---------------------------------------------------------------------------
// front: one block per row i (512 threads).
//   stage1: yq/yk/yv row = x_row @ {Wq,Wk,Wv} (bf16 transposed weights)
//   stage2: a_i[h,i,:] = yq[h-slice] @ W1q + coords@W1ci
//           a_j[h,i,:] = yk[h-slice] @ W1k + coords@W1cj + b1
// ---------------------------------------------------------------------------
__global__ __launch_bounds__(512) void front_kernel(
    const float* __restrict__ x, const float* __restrict__ coords,
    const ushort* __restrict__ wT, const float* __restrict__ W1,
    const float* __restrict__ b1, float* __restrict__ ai,
    float* __restrict__ aj, float* __restrict__ yv)
{
    const int i = blockIdx.x, t = threadIdx.x;
    __shared__ float xs[512], cs[64], yqs[512], yks[512];
    xs[t] = x[(long)i * D_ + t];
    if (t < 64) cs[t] = coords[(long)i * M_ + t];
    __syncthreads();

    // ---- stage 1: thread t owns output column t of yq,yk,yv
    {
        const ushort* wq = wT + (long)t * D_;
        const ushort* wk = wq + D_ * D_;
        const ushort* wv = wk + D_ * D_;
        float aq = 0.f, ak = 0.f, av = 0.f;
        for (int k0 = 0; k0 < 512; k0 += 8) {
            ushort4 q0 = *(const ushort4*)(wq + k0), q1 = *(const ushort4*)(wq + k0 + 4);
            ushort4 s0 = *(const ushort4*)(wk + k0), s1 = *(const ushort4*)(wk + k0 + 4);
            ushort4 v0 = *(const ushort4*)(wv + k0), v1 = *(const ushort4*)(wv + k0 + 4);
            float xv[8];
            #pragma unroll
            for (int e = 0; e < 8; ++e) xv[e] = xs[k0 + e];
            aq = fmaf(xv[0], bf2f(q0.x), aq); aq = fmaf(xv[1], bf2f(q0.y), aq);
            aq = fmaf(xv[2], bf2f(q0.z), aq); aq = fmaf(xv[3], bf2f(q0.w), aq);
            aq = fmaf(xv[4], bf2f(q1.x), aq); aq = fmaf(xv[5], bf2f(q1.y), aq);
            aq = fmaf(xv[6], bf2f(q1.z), aq); aq = fmaf(xv[7], bf2f(q1.w), aq);
            ak = fmaf(xv[0], bf2f(s0.x), ak); ak = fmaf(xv[1], bf2f(s0.y), ak);
            ak = fmaf(xv[2], bf2f(s0.z), ak); ak = fmaf(xv[3], bf2f(s0.w), ak);
            ak = fmaf(xv[4], bf2f(s1.x), ak); ak = fmaf(xv[5], bf2f(s1.y), ak);
            ak = fmaf(xv[6], bf2f(s1.z), ak); ak = fmaf(xv[7], bf2f(s1.w), ak);
            av = fmaf(xv[0], bf2f(v0.x), av); av = fmaf(xv[1], bf2f(v0.y), av);
            av = fmaf(xv[2], bf2f(v0.z), av); av = fmaf(xv[3], bf2f(v0.w), av);
            av = fmaf(xv[4], bf2f(v1.x), av); av = fmaf(xv[5], bf2f(v1.y), av);
            av = fmaf(xv[6], bf2f(v1.z), av); av = fmaf(xv[7], bf2f(v1.w), av);
        }
        yqs[t] = aq; yks[t] = ak;
        yv[(long)i * D_ + t] = av;
    }
    __syncthreads();

    // ---- stage 2: thread t -> feature f = t&255, heads {hb, hb+2, hb+4, hb+6}
    const int f = t & 255, hb = t >> 8;
    float ciacc = 0.f, cjacc = 0.f;
    for (int m = 0; m < 64; ++m) {
        float cv = cs[m];
        ciacc = fmaf(cv, W1[(128 + m) * 256 + f], ciacc);
        cjacc = fmaf(cv, W1[(192 + m) * 256 + f], cjacc);
    }
    float aI0 = ciacc, aI1 = ciacc, aI2 = ciacc, aI3 = ciacc;
    float aJ0 = cjacc, aJ1 = cjacc, aJ2 = cjacc, aJ3 = cjacc;
    for (int d = 0; d < 64; ++d) {
        float wq1 = W1[d * 256 + f];
        float wk1 = W1[(64 + d) * 256 + f];
        aI0 = fmaf(yqs[(hb + 0) * 64 + d], wq1, aI0);
        aI1 = fmaf(yqs[(hb + 2) * 64 + d], wq1, aI1);
        aI2 = fmaf(yqs[(hb + 4) * 64 + d], wq1, aI2);
        aI3 = fmaf(yqs[(hb + 6) * 64 + d], wq1, aI3);
        aJ0 = fmaf(yks[(hb + 0) * 64 + d], wk1, aJ0);
        aJ1 = fmaf(yks[(hb + 2) * 64 + d], wk1, aJ1);
        aJ2 = fmaf(yks[(hb + 4) * 64 + d], wk1, aJ2);
        aJ3 = fmaf(yks[(hb + 6) * 64 + d], wk1, aJ3);
    }
    const float b1f = b1[f];
    ai[((long)(hb + 0) * T_ + i) * 256 + f] = aI0;
    ai[((long)(hb + 2) * T_ + i) * 256 + f] = aI1;
    ai[((long)(hb + 4) * T_ + i) * 256 + f] = aI2;
    ai[((long)(hb + 6) * T_ + i) * 256 + f] = aI3;
    aj[((long)(hb + 0) * T_ + i) * 256 + f] = aJ0 + b1f;
    aj[((long)(hb + 2) * T_ + i) * 256 + f] = aJ1 + b1f;
    aj[((long)(hb + 4) * T_ + i) * 256 + f] = aJ2 + b1f;
    aj[((long)(hb + 6) * T_ + i) * 256 + f] = aJ3 + b1f;
}

// ---------------------------------------------------------------------------
// pairwise v4: 32x32 (i,j) tile, feature-split in 2 (128 features per block).
// Writes RAW partial sums (no b2d, no tanh) to pb[hs][i][j], hs = h*2+sp.
// Grid (8 jt, 8 it, 16 hs) = 1024 blocks x 256.
// ---------------------------------------------------------------------------
#define SILU_ACC(acc, w, aa, bb) \
    { float t_ = (aa) + (bb); \
      float sg_ = __builtin_amdgcn_rcpf(1.f + __expf(-t_)); \
      acc = fmaf((w) * t_, sg_, acc); }

__global__ __launch_bounds__(256) void pairwise_kernel(
    const float* __restrict__ a_i, const float* __restrict__ a_j,
    const float* __restrict__ W2, float* __restrict__ pb)
{
    const int jt = blockIdx.x, it = blockIdx.y, hs = blockIdx.z;
    const int h = hs >> 1, fb = (hs & 1) * 128;
    const int t = threadIdx.x;

    __shared__ __align__(16) float ai_s[32][132];
    __shared__ __align__(16) float aj_s[32][132];
    __shared__ __align__(16) float w2d[128];

    if (t < 128) w2d[t] = W2[(fb + t) * 2 + 0] - W2[(fb + t) * 2 + 1];

    const float* aib = a_i + ((long)h * T_ + it * 32) * 256 + fb;
    const float* ajb = a_j + ((long)h * T_ + jt * 32) * 256 + fb;
    #pragma unroll
    for (int l = 0; l < 4; ++l) {
        int idx = t + l * 256;          // float4 id 0..1023
        int r = idx >> 5, c4 = idx & 31;
        *(float4*)&ai_s[r][c4 * 4] = *(const float4*)(aib + (long)r * 256 + c4 * 4);
        *(float4*)&aj_s[r][c4 * 4] = *(const float4*)(ajb + (long)r * 256 + c4 * 4);
    }
    __syncthreads();

    const int ty = t >> 4, tx = t & 15;
    float s00 = 0.f, s01 = 0.f, s10 = 0.f, s11 = 0.f;

    #pragma unroll
    for (int fc = 0; fc < 2; ++fc) {
        const float* wp = &w2d[fc * 64];
        #pragma unroll 4
        for (int f4 = 0; f4 < 16; ++f4) {
            float4 a0 = *(const float4*)&ai_s[ty][fc * 64 + f4 * 4];
            float4 a1 = *(const float4*)&ai_s[ty + 16][fc * 64 + f4 * 4];
            float4 c0 = *(const float4*)&aj_s[tx][fc * 64 + f4 * 4];
            float4 c1 = *(const float4*)&aj_s[tx + 16][fc * 64 + f4 * 4];
            float4 w  = *(const float4*)&wp[f4 * 4];
            SILU_ACC(s00, w.x, a0.x, c0.x); SILU_ACC(s01, w.x, a0.x, c1.x);
            SILU_ACC(s10, w.x, a1.x, c0.x); SILU_ACC(s11, w.x, a1.x, c1.x);
            SILU_ACC(s00, w.y, a0.y, c0.y); SILU_ACC(s01, w.y, a0.y, c1.y);
            SILU_ACC(s10, w.y, a1.y, c0.y); SILU_ACC(s11, w.y, a1.y, c1.y);
            SILU_ACC(s00, w.z, a0.z, c0.z); SILU_ACC(s01, w.z, a0.z, c1.z);
            SILU_ACC(s10, w.z, a1.z, c0.z); SILU_ACC(s11, w.z, a1.z, c1.z);
            SILU_ACC(s00, w.w, a0.w, c0.w); SILU_ACC(s01, w.w, a0.w, c1.w);
            SILU_ACC(s10, w.w, a1.w, c0.w); SILU_ACC(s11, w.w, a1.w, c1.w);
        }
    }

    const int gi0 = it * 32 + ty, gi1 = gi0 + 16;
    const int gj0 = jt * 32 + tx, gj1 = gj0 + 16;
    float* pbh = pb + (long)hs * (T_ * T_);
    pbh[(long)gi0 * T_ + gj0] = s00;
    pbh[(long)gi0 * T_ + gj1] = s01;
    pbh[(long)gi1 * T_ + gj0] = s10;
    pbh[(long)gi1 * T_ + gj1] = s11;
}

// ---------------------------------------------------------------------------
// back: one block per row i (512 threads).
//   tanh(partials) -> causal softmax (per-head wave) -> PV -> 3-GEMM epilogue
//   (bf16 transposed W3/W4/Wo streamed). Emits writhe/|lk| partials per row.
// ---------------------------------------------------------------------------
__global__ __launch_bounds__(512) void back_kernel(
    const float* __restrict__ pb, const float* __restrict__ yv,
    const ushort* __restrict__ wT3, const float* __restrict__ b2,
    const float* __restrict__ b3, const float* __restrict__ b4,
    float* __restrict__ out, float* __restrict__ parts)
{
    const int i = blockIdx.x, t = threadIdx.x;
    const int w = t >> 6, lane = t & 63;

    __shared__ float p[8][256];
    __shared__ float os[512], g1s[512];
    __shared__ float psc[8];

    const float b2d = b2[0] - b2[1];

    // ---- per-wave: head w. linking + causal softmax + writhe partials
    const float* pb0 = pb + ((long)(2 * w + 0) * T_ + i) * T_;
    const float* pb1 = pb + ((long)(2 * w + 1) * T_ + i) * T_;
    float sv[4];
    float mx = -1e30f, wsum = 0.f, asum = 0.f;
    #pragma unroll
    for (int r = 0; r < 4; ++r) {
        int j = lane + r * 64;
        float s = pb0[j] + pb1[j] + b2d;
        float as = fabsf(s);
        float e = __expf(-as);
        float tv = (1.f - e) * __builtin_amdgcn_rcpf(1.f + e);   // tanh(|s|/2)... = tanh(as/2)*?  == (1-e^-as)/(1+e^-as) = tanh(as/2)
        float lk = (s < 0.f) ? -tv : tv;                          // tanh(s/2)
        wsum += lk; asum += fabsf(lk);
        float sc = (j <= i) ? lk * 0.125f : -1e30f;
        sv[r] = sc; mx = fmaxf(mx, sc);
    }
    #pragma unroll
    for (int off = 32; off > 0; off >>= 1) mx = fmaxf(mx, __shfl_xor(mx, off));
    float sum = 0.f;
    #pragma unroll
    for (int r = 0; r < 4; ++r) {
        int j = lane + r * 64;
        float e = (j <= i) ? __expf(sv[r] - mx) : 0.f;
        p[w][j] = e; sum += e;
    }
    #pragma unroll
    for (int off = 32; off > 0; off >>= 1) {
        sum  += __shfl_xor(sum, off);
        wsum += __shfl_xor(wsum, off);
        asum += __shfl_xor(asum, off);
    }
    if (lane == 0) {
        psc[w] = __builtin_amdgcn_rcpf(sum);
        parts[((long)i * 8 + w) * 2 + 0] = wsum;
        parts[((long)i * 8 + w) * 2 + 1] = asum;
    }
    __syncthreads();

    // ---- PV: thread t owns output col c
    const int c = t, h2 = t >> 6;
    {
        const float pinv = psc[h2];
        const float* vb = yv + c;
        float acc = 0.f;
        for (int j = 0; j <= i; ++j) acc = fmaf(p[h2][j], vb[(long)j * D_], acc);
        os[c] = acc * pinv;
    }
    __syncthreads();

    // ---- g1 = silu(o @ W3 + b3)
    {
        const ushort* wr = wT3 + (long)c * D_;
        float g = 0.f;
        for (int k0 = 0; k0 < 512; k0 += 8) {
            ushort4 u0 = *(const ushort4*)(wr + k0), u1 = *(const ushort4*)(wr + k0 + 4);
            g = fmaf(os[k0 + 0], bf2f(u0.x), g); g = fmaf(os[k0 + 1], bf2f(u0.y), g);
            g = fmaf(os[k0 + 2], bf2f(u0.z), g); g = fmaf(os[k0 + 3], bf2f(u0.w), g);
            g = fmaf(os[k0 + 4], bf2f(u1.x), g); g = fmaf(os[k0 + 5], bf2f(u1.y), g);
            g = fmaf(os[k0 + 6], bf2f(u1.z), g); g = fmaf(os[k0 + 7], bf2f(u1.w), g);
        }
        g += b3[c];
        g = g * __builtin_amdgcn_rcpf(1.f + __expf(-g));
        g1s[c] = g;
    }
    __syncthreads();

    // ---- g2 = g1 @ W4 + b4  (write into os, all g1s-producing reads done)
    {
        const ushort* wr = wT3 + (long)(D_ * D_) + (long)c * D_;
        float g = 0.f;
        for (int k0 = 0; k0 < 512; k0 += 8) {
            ushort4 u0 = *(const ushort4*)(wr + k0), u1 = *(const ushort4*)(wr + k0 + 4);
            g = fmaf(g1s[k0 + 0], bf2f(u0.x), g); g = fmaf(g1s[k0 + 1], bf2f(u0.y), g);
            g = fmaf(g1s[k0 + 2], bf2f(u0.z), g); g = fmaf(g1s[k0 + 3], bf2f(u0.w), g);
            g = fmaf(g1s[k0 + 4], bf2f(u1.x), g); g = fmaf(g1s[k0 + 5], bf2f(u1.y), g);
            g = fmaf(g1s[k0 + 6], bf2f(u1.z), g); g = fmaf(g1s[k0 + 7], bf2f(u1.w), g);
        }
        os[c] = g + b4[c];
    }
    __syncthreads();

    // ---- out_row = g2 @ Wo
    {
        const ushort* wr = wT3 + (long)(2 * D_ * D_) + (long)c * D_;
        float g = 0.f;
        for (int k0 = 0; k0 < 512; k0 += 8) {
            ushort4 u0 = *(const ushort4*)(wr + k0), u1 = *(const ushort4*)(wr + k0 + 4);
            g = fmaf(os[k0 + 0], bf2f(u0.x), g); g = fmaf(os[k0 + 1], bf2f(u0.y), g);
            g = fmaf(os[k0 + 2], bf2f(u0.z), g); g = fmaf(os[k0 + 3], bf2f(u0.w), g);
            g = fmaf(os[k0 + 4], bf2f(u1.x), g); g = fmaf(os[k0 + 5], bf2f(u1.y), g);
            g = fmaf(os[k0 + 6], bf2f(u1.z), g); g = fmaf(os[k0 + 7], bf2f(u1.w), g);
        }
        out[(long)i * D_ + c] = g;
    }
}

// ---------------------------------------------------------------------------
// tail: writhe[8] + linking_mean from 256x8 row partials.
// ---------------------------------------------------------------------------
__global__ __launch_bounds__(64) void tail_kernel(
    const float* __restrict__ parts, float* __restrict__ tailo)
{
    const int lane = threadIdx.x;
    if (lane < 8) {
        float wsum = 0.f;
        for (int i = 0; i < 256; ++i) wsum += parts[((long)i * 8 + lane) * 2 + 0];
        tailo[lane] = wsum;
    }
    float a = 0.f;
    for (int idx = lane; idx < 2048; idx += 64) a += parts[(long)idx * 2 + 1];
    #pragma unroll
    for (int off = 32; off > 0; off >>= 1) a += __shfl_xor(a, off);
    if (lane == 0) tailo[8] = a / (float)(H_ * T_ * T_);
}

// ---------------------------------------------------------------------------
extern "C" void kernel_launch(void* const* d_in, const int* in_sizes, int n_in,
                              void* d_out, int out_size, void* d_ws, size_t ws_size,
                              hipStream_t stream)
{
    const float* x      = (const float*)d_in[0];
    const float* coords = (const float*)d_in[1];
    const float* Wq     = (const float*)d_in[2];
    const float* Wk     = (const float*)d_in[3];
    const float* Wv     = (const float*)d_in[4];
    const float* Wo     = (const float*)d_in[5];
    const float* W1     = (const float*)d_in[6];
    const float* b1     = (const float*)d_in[7];
    const float* W2     = (const float*)d_in[8];
    const float* b2     = (const float*)d_in[9];
    const float* W3     = (const float*)d_in[10];
    const float* b3     = (const float*)d_in[11];
    const float* W4     = (const float*)d_in[12];
    const float* b4     = (const float*)d_in[13];
    float* out = (float*)d_out;

    float* ws = (float*)d_ws;
    ushort* wT   = (ushort*)ws;           // 6 * 512*512 bf16 = 786432 floats
    float* ai    = ws + 786432;           // 8*256*256
    float* aj    = ws + 1310720;          // 8*256*256
    float* yv    = ws + 1835008;          // 256*512
    float* pb    = ws + 1966080;          // 16*256*256
    float* parts = ws + 3014656;          // 256*8*2

    // 1) weight transpose+bf16 (q,k,v,3,4,o)
    prep_kernel<<<dim3(16, 16, 6), dim3(256), 0, stream>>>(Wq, Wk, Wv, W3, W4, Wo, wT);

    // 2) front: x-row -> yv + a_i/a_j rows
    front_kernel<<<dim3(T_), dim3(512), 0, stream>>>(x, coords, wT, W1, b1, ai, aj, yv);

    // 3) pairwise silu-MLP partial sums (feature-split 2x)
    pairwise_kernel<<<dim3(8, 8, 16), dim3(256), 0, stream>>>(ai, aj, W2, pb);

    // 4) back: tanh -> softmax -> PV -> 3-GEMM epilogue (+ row partials)
    back_kernel<<<dim3(T_), dim3(512), 0, stream>>>(
        pb, yv, wT + (long)3 * D_ * D_, b2, b3, b4, out, parts);

    // 5) tail reduce: writhe + linking_mean
    tail_kernel<<<dim3(1), dim3(64), 0, stream>>>(parts, out + 131072);
}

// Round 6
// 137.080 us; speedup vs baseline: 1.5557x; 1.5557x over previous
//
#include <hip/hip_runtime.h>
#include <math.h>

// Problem constants: B=1, T=256, D=512, M=64, H=8, HD=64, IN=256, HID=256
#define T_ 256
#define D_ 512
#define M_ 64
#define H_ 8
#define HD_ 64
#define HID_ 256

// ---------------------------------------------------------------------------
// fp32 vector GEMM engine: 32x32 tile, 256 threads, 2x2 micro-tile.
// float4 staging, 16B-aligned LDS rows (pad 36), conflict-free inner reads.
// ---------------------------------------------------------------------------

// ---- epilogue GEMM: C = act(A @ B + bias), M=256, N=512, K=512, grid (16,8)
__global__ __launch_bounds__(256) void mm32_kernel(
    const float* __restrict__ A, const float* __restrict__ B,
    float* __restrict__ C, const float* __restrict__ bias, int act)
{
    __shared__ __align__(16) float As[32][36];
    __shared__ __align__(16) float Bs[32][36];

    const int tid = threadIdx.x;
    const int tx = tid & 15, ty = tid >> 4;
    const int row0 = blockIdx.y * 32, col0 = blockIdx.x * 32;
    const int r4 = tid >> 3, c4 = tid & 7;     // staging: row 0..31, col4 0..7

    float acc00 = 0.f, acc01 = 0.f, acc10 = 0.f, acc11 = 0.f;

    for (int k0 = 0; k0 < D_; k0 += 32) {
        *(float4*)&As[r4][c4 * 4] = *(const float4*)(A + (long)(row0 + r4) * D_ + k0 + c4 * 4);
        *(float4*)&Bs[r4][c4 * 4] = *(const float4*)(B + (long)(k0 + r4) * D_ + col0 + c4 * 4);
        __syncthreads();
        #pragma unroll
        for (int kk = 0; kk < 32; ++kk) {
            float a0 = As[ty * 2 + 0][kk];
            float a1 = As[ty * 2 + 1][kk];
            float b0 = Bs[kk][tx * 2 + 0];
            float b1 = Bs[kk][tx * 2 + 1];
            acc00 = fmaf(a0, b0, acc00); acc01 = fmaf(a0, b1, acc01);
            acc10 = fmaf(a1, b0, acc10); acc11 = fmaf(a1, b1, acc11);
        }
        __syncthreads();
    }

    float accs[2][2] = {{acc00, acc01}, {acc10, acc11}};
    #pragma unroll
    for (int ii = 0; ii < 2; ++ii) {
        #pragma unroll
        for (int jj = 0; jj < 2; ++jj) {
            int r = row0 + ty * 2 + ii, c = col0 + tx * 2 + jj;
            float v = accs[ii][jj];
            if (bias) v += bias[c];
            if (act)  v = v * __builtin_amdgcn_rcpf(1.f + __expf(-v));  // silu
            C[(long)r * D_ + c] = v;
        }
    }
}

// ---- fused QKV: y[z] = x @ W[z], grid (16, 8, 3)
__global__ __launch_bounds__(256) void qkv_kernel(
    const float* __restrict__ x,
    const float* __restrict__ Wq, const float* __restrict__ Wk,
    const float* __restrict__ Wv, float* __restrict__ y)
{
    __shared__ __align__(16) float As[32][36];
    __shared__ __align__(16) float Bs[32][36];

    const int z = blockIdx.z;
    const float* W = (z == 0) ? Wq : (z == 1) ? Wk : Wv;
    float* C = y + (long)z * (T_ * D_);

    const int tid = threadIdx.x;
    const int tx = tid & 15, ty = tid >> 4;
    const int row0 = blockIdx.y * 32, col0 = blockIdx.x * 32;
    const int r4 = tid >> 3, c4 = tid & 7;

    float acc00 = 0.f, acc01 = 0.f, acc10 = 0.f, acc11 = 0.f;

    for (int k0 = 0; k0 < D_; k0 += 32) {
        *(float4*)&As[r4][c4 * 4] = *(const float4*)(x + (long)(row0 + r4) * D_ + k0 + c4 * 4);
        *(float4*)&Bs[r4][c4 * 4] = *(const float4*)(W + (long)(k0 + r4) * D_ + col0 + c4 * 4);
        __syncthreads();
        #pragma unroll
        for (int kk = 0; kk < 32; ++kk) {
            float a0 = As[ty * 2 + 0][kk];
            float a1 = As[ty * 2 + 1][kk];
            float b0 = Bs[kk][tx * 2 + 0];
            float b1 = Bs[kk][tx * 2 + 1];
            acc00 = fmaf(a0, b0, acc00); acc01 = fmaf(a0, b1, acc01);
            acc10 = fmaf(a1, b0, acc10); acc11 = fmaf(a1, b1, acc11);
        }
        __syncthreads();
    }
    C[(long)(row0 + ty * 2 + 0) * D_ + col0 + tx * 2 + 0] = acc00;
    C[(long)(row0 + ty * 2 + 0) * D_ + col0 + tx * 2 + 1] = acc01;
    C[(long)(row0 + ty * 2 + 1) * D_ + col0 + tx * 2 + 0] = acc10;
    C[(long)(row0 + ty * 2 + 1) * D_ + col0 + tx * 2 + 1] = acc11;
}

// ---- a_i / a_j with coords via K-concat (K = 64 + 64), grid (8, 8, 16)
//   z = sel*8 + h : abuf[z] = [ y[sel][:,h*64:+64] | coords ] @
//                             [ W1[sel*64:+64] ; W1[128+64*sel:+64] ] (+b1 if sel)
__global__ __launch_bounds__(256) void aiaj_kernel(
    const float* __restrict__ y, const float* __restrict__ coords,
    const float* __restrict__ W1, const float* __restrict__ b1,
    float* __restrict__ abuf)
{
    __shared__ __align__(16) float As[32][36];
    __shared__ __align__(16) float Bs[32][36];

    const int z = blockIdx.z;
    const int sel = z >> 3, h = z & 7;
    const float* Ay = y + (long)sel * (T_ * D_) + h * HD_;
    float* C = abuf + (long)z * (T_ * HID_);

    const int tid = threadIdx.x;
    const int tx = tid & 15, ty = tid >> 4;
    const int row0 = blockIdx.y * 32, col0 = blockIdx.x * 32;
    const int r4 = tid >> 3, c4 = tid & 7;

    float acc00 = 0.f, acc01 = 0.f, acc10 = 0.f, acc11 = 0.f;

    for (int k0 = 0; k0 < 128; k0 += 32) {
        if (k0 < 64) {
            *(float4*)&As[r4][c4 * 4] =
                *(const float4*)(Ay + (long)(row0 + r4) * D_ + k0 + c4 * 4);
            *(float4*)&Bs[r4][c4 * 4] =
                *(const float4*)(W1 + (long)(sel * 64 + k0 + r4) * HID_ + col0 + c4 * 4);
        } else {
            *(float4*)&As[r4][c4 * 4] =
                *(const float4*)(coords + (long)(row0 + r4) * M_ + (k0 - 64) + c4 * 4);
            *(float4*)&Bs[r4][c4 * 4] =
                *(const float4*)(W1 + (long)(128 + 64 * sel + k0 - 64 + r4) * HID_ + col0 + c4 * 4);
        }
        __syncthreads();
        #pragma unroll
        for (int kk = 0; kk < 32; ++kk) {
            float a0 = As[ty * 2 + 0][kk];
            float a1 = As[ty * 2 + 1][kk];
            float b0 = Bs[kk][tx * 2 + 0];
            float b1 = Bs[kk][tx * 2 + 1];
            acc00 = fmaf(a0, b0, acc00); acc01 = fmaf(a0, b1, acc01);
            acc10 = fmaf(a1, b0, acc10); acc11 = fmaf(a1, b1, acc11);
        }
        __syncthreads();
    }
    const int c0 = col0 + tx * 2, r0 = row0 + ty * 2;
    float bb0 = (sel == 1) ? b1[c0 + 0] : 0.f;
    float bb1 = (sel == 1) ? b1[c0 + 1] : 0.f;
    C[(long)(r0 + 0) * HID_ + c0 + 0] = acc00 + bb0;
    C[(long)(r0 + 0) * HID_ + c0 + 1] = acc01 + bb1;
    C[(long)(r0 + 1) * HID_ + c0 + 0] = acc10 + bb0;
    C[(long)(r0 + 1) * HID_ + c0 + 1] = acc11 + bb1;
}

// ---------------------------------------------------------------------------
// pairwise v4: 32x32 (i,j) tile, feature-split in 2 (128 features per block).
// Writes RAW partial sums (no b2d, no tanh) to pb[hs][i][j], hs = h*2+sp.
// Grid (8 jt, 8 it, 16 hs) = 1024 blocks x 256.
// ---------------------------------------------------------------------------
#define SILU_ACC(acc, w, aa, bb) \
    { float t_ = (aa) + (bb); \
      float sg_ = __builtin_amdgcn_rcpf(1.f + __expf(-t_)); \
      acc = fmaf((w) * t_, sg_, acc); }

__global__ __launch_bounds__(256) void pairwise_kernel(
    const float* __restrict__ a_i, const float* __restrict__ a_j,
    const float* __restrict__ W2, float* __restrict__ pb)
{
    const int jt = blockIdx.x, it = blockIdx.y, hs = blockIdx.z;
    const int h = hs >> 1, fb = (hs & 1) * 128;
    const int t = threadIdx.x;

    __shared__ __align__(16) float ai_s[32][132];
    __shared__ __align__(16) float aj_s[32][132];
    __shared__ __align__(16) float w2d[128];

    if (t < 128) w2d[t] = W2[(fb + t) * 2 + 0] - W2[(fb + t) * 2 + 1];

    const float* aib = a_i + ((long)h * T_ + it * 32) * HID_ + fb;
    const float* ajb = a_j + ((long)h * T_ + jt * 32) * HID_ + fb;
    #pragma unroll
    for (int l = 0; l < 4; ++l) {
        int idx = t + l * 256;          // float4 id 0..1023
        int r = idx >> 5, c4 = idx & 31;
        *(float4*)&ai_s[r][c4 * 4] = *(const float4*)(aib + (long)r * HID_ + c4 * 4);
        *(float4*)&aj_s[r][c4 * 4] = *(const float4*)(ajb + (long)r * HID_ + c4 * 4);
    }
    __syncthreads();

    const int ty = t >> 4, tx = t & 15;
    float s00 = 0.f, s01 = 0.f, s10 = 0.f, s11 = 0.f;

    #pragma unroll
    for (int fc = 0; fc < 2; ++fc) {
        const float* wp = &w2d[fc * 64];
        #pragma unroll 4
        for (int f4 = 0; f4 < 16; ++f4) {
            float4 a0 = *(const float4*)&ai_s[ty][fc * 64 + f4 * 4];
            float4 a1 = *(const float4*)&ai_s[ty + 16][fc * 64 + f4 * 4];
            float4 c0 = *(const float4*)&aj_s[tx][fc * 64 + f4 * 4];
            float4 c1 = *(const float4*)&aj_s[tx + 16][fc * 64 + f4 * 4];
            float4 w  = *(const float4*)&wp[f4 * 4];
            SILU_ACC(s00, w.x, a0.x, c0.x); SILU_ACC(s01, w.x, a0.x, c1.x);
            SILU_ACC(s10, w.x, a1.x, c0.x); SILU_ACC(s11, w.x, a1.x, c1.x);
            SILU_ACC(s00, w.y, a0.y, c0.y); SILU_ACC(s01, w.y, a0.y, c1.y);
            SILU_ACC(s10, w.y, a1.y, c0.y); SILU_ACC(s11, w.y, a1.y, c1.y);
            SILU_ACC(s00, w.z, a0.z, c0.z); SILU_ACC(s01, w.z, a0.z, c1.z);
            SILU_ACC(s10, w.z, a1.z, c0.z); SILU_ACC(s11, w.z, a1.z, c1.z);
            SILU_ACC(s00, w.w, a0.w, c0.w); SILU_ACC(s01, w.w, a0.w, c1.w);
            SILU_ACC(s10, w.w, a1.w, c0.w); SILU_ACC(s11, w.w, a1.w, c1.w);
        }
    }

    const int gi0 = it * 32 + ty, gi1 = gi0 + 16;
    const int gj0 = jt * 32 + tx, gj1 = gj0 + 16;
    float* pbh = pb + (long)hs * (T_ * T_);
    pbh[(long)gi0 * T_ + gj0] = s00;
    pbh[(long)gi0 * T_ + gj1] = s01;
    pbh[(long)gi1 * T_ + gj0] = s10;
    pbh[(long)gi1 * T_ + gj1] = s11;
}

// ---------------------------------------------------------------------------
// attn: one block per row i (512 threads = 8 waves = 8 heads).
// Merge pb halves + b2d -> tanh -> causal softmax -> PV -> o row.
// Also emits per-(i,h) writhe / |linking| partials.
// ---------------------------------------------------------------------------
__global__ __launch_bounds__(512) void attn_kernel(
    const float* __restrict__ pb, const float* __restrict__ yv,
    const float* __restrict__ b2, float* __restrict__ o,
    float* __restrict__ parts)
{
    const int i = blockIdx.x, t = threadIdx.x;
    const int w = t >> 6, lane = t & 63;

    __shared__ float p[8][256];
    __shared__ float psc[8];

    const float b2d = b2[0] - b2[1];

    const float* pb0 = pb + ((long)(2 * w + 0) * T_ + i) * T_;
    const float* pb1 = pb + ((long)(2 * w + 1) * T_ + i) * T_;
    float sv[4];
    float mx = -1e30f, wsum = 0.f, asum = 0.f;
    #pragma unroll
    for (int r = 0; r < 4; ++r) {
        int j = lane + r * 64;
        float s = pb0[j] + pb1[j] + b2d;
        float as = fabsf(s);
        float e = __expf(-as);
        float tv = (1.f - e) * __builtin_amdgcn_rcpf(1.f + e);   // tanh(|s|/2)
        float lk = (s < 0.f) ? -tv : tv;                          // tanh(s/2)
        wsum += lk; asum += fabsf(lk);
        float sc = (j <= i) ? lk * 0.125f : -1e30f;
        sv[r] = sc; mx = fmaxf(mx, sc);
    }
    #pragma unroll
    for (int off = 32; off > 0; off >>= 1) mx = fmaxf(mx, __shfl_xor(mx, off));
    float sum = 0.f;
    #pragma unroll
    for (int r = 0; r < 4; ++r) {
        int j = lane + r * 64;
        float e = (j <= i) ? __expf(sv[r] - mx) : 0.f;
        p[w][j] = e; sum += e;
    }
    #pragma unroll
    for (int off = 32; off > 0; off >>= 1) {
        sum  += __shfl_xor(sum, off);
        wsum += __shfl_xor(wsum, off);
        asum += __shfl_xor(asum, off);
    }
    if (lane == 0) {
        psc[w] = __builtin_amdgcn_rcpf(sum);
        parts[((long)i * 8 + w) * 2 + 0] = wsum;
        parts[((long)i * 8 + w) * 2 + 1] = asum;
    }
    __syncthreads();

    // PV: thread t owns output column t (head w = t>>6, d = lane)
    const float pinv = psc[w];
    const float* vb = yv + t;
    float a0 = 0.f, a1 = 0.f, a2 = 0.f, a3 = 0.f;
    int j = 0;
    for (; j + 3 <= i; j += 4) {
        a0 = fmaf(p[w][j + 0], vb[(long)(j + 0) * D_], a0);
        a1 = fmaf(p[w][j + 1], vb[(long)(j + 1) * D_], a1);
        a2 = fmaf(p[w][j + 2], vb[(long)(j + 2) * D_], a2);
        a3 = fmaf(p[w][j + 3], vb[(long)(j + 3) * D_], a3);
    }
    for (; j <= i; ++j) a0 = fmaf(p[w][j], vb[(long)j * D_], a0);
    o[(long)i * D_ + t] = ((a0 + a1) + (a2 + a3)) * pinv;
}

// ---------------------------------------------------------------------------
// tail: writhe[8] + linking_mean from 256x8 row partials.
// ---------------------------------------------------------------------------
__global__ __launch_bounds__(64) void tail_kernel(
    const float* __restrict__ parts, float* __restrict__ tailo)
{
    const int lane = threadIdx.x;
    if (lane < 8) {
        float wsum = 0.f;
        for (int i = 0; i < 256; ++i) wsum += parts[((long)i * 8 + lane) * 2 + 0];
        tailo[lane] = wsum;
    }
    float a = 0.f;
    for (int idx = lane; idx < 2048; idx += 64) a += parts[(long)idx * 2 + 1];
    #pragma unroll
    for (int off = 32; off > 0; off >>= 1) a += __shfl_xor(a, off);
    if (lane == 0) tailo[8] = a / (float)(H_ * T_ * T_);
}

// ---------------------------------------------------------------------------
extern "C" void kernel_launch(void* const* d_in, const int* in_sizes, int n_in,
                              void* d_out, int out_size, void* d_ws, size_t ws_size,
                              hipStream_t stream)
{
    const float* x      = (const float*)d_in[0];
    const float* coords = (const float*)d_in[1];
    const float* Wq     = (const float*)d_in[2];
    const float* Wk     = (const float*)d_in[3];
    const float* Wv     = (const float*)d_in[4];
    const float* Wo     = (const float*)d_in[5];
    const float* W1     = (const float*)d_in[6];
    const float* b1     = (const float*)d_in[7];
    const float* W2     = (const float*)d_in[8];
    const float* b2     = (const float*)d_in[9];
    const float* W3     = (const float*)d_in[10];
    const float* b3     = (const float*)d_in[11];
    const float* W4     = (const float*)d_in[12];
    const float* b4     = (const float*)d_in[13];
    float* out = (float*)d_out;

    float* ws = (float*)d_ws;
    float* y     = ws;                    // 3 * 256*512       = 393216
    float* ai    = ws + 393216;           // abuf: ai = [0..7], aj = [8..15]
    float* aj    = ws + 917504;           //   (contiguous, aj = ai + 8*T*HID)
    float* pb    = ws + 1441792;          // 16*256*256        = 1048576
    float* o     = ws + 2490368;          // 256*512
    float* g1    = ws + 2621440;
    float* g2    = ws + 2752512;
    float* parts = ws + 2883584;          // 256*8*2

    // 1) q,k,v projections
    qkv_kernel<<<dim3(16, 8, 3), dim3(256), 0, stream>>>(x, Wq, Wk, Wv, y);

    // 2) a_i / a_j (coords K-concat, b1 folded); single contiguous abuf at ai
    aiaj_kernel<<<dim3(8, 8, 16), dim3(256), 0, stream>>>(y, coords, W1, b1, ai);

    // 3) pairwise silu-MLP raw partials (feature-split 2x)
    pairwise_kernel<<<dim3(8, 8, 16), dim3(256), 0, stream>>>(ai, aj, W2, pb);

    // 4) tanh -> causal softmax -> PV (+ row partials)
    attn_kernel<<<dim3(T_), dim3(512), 0, stream>>>(pb, y + 2 * (T_ * D_), b2, o, parts);

    // 5) epilogue: out = (silu(o@W3+b3) @ W4 + b4) @ Wo
    mm32_kernel<<<dim3(16, 8), dim3(256), 0, stream>>>(o,  W3, g1,  b3, 1);
    mm32_kernel<<<dim3(16, 8), dim3(256), 0, stream>>>(g1, W4, g2,  b4, 0);
    mm32_kernel<<<dim3(16, 8), dim3(256), 0, stream>>>(g2, Wo, out, nullptr, 0);

    // 6) tail reduce: writhe + linking_mean
    tail_kernel<<<dim3(1), dim3(64), 0, stream>>>(parts, out + 131072);
}

// Round 7
// 119.353 us; speedup vs baseline: 1.7867x; 1.1485x over previous
//
#include <hip/hip_runtime.h>
#include <math.h>

// Problem constants: B=1, T=256, D=512, M=64, H=8, HD=64, IN=256, HID=256
#define T_ 256
#define D_ 512
#define M_ 64
#define H_ 8
#define HD_ 64
#define HID_ 256

// ---------------------------------------------------------------------------
// fp32 vector GEMM engine: 32x32 tile, 256 threads, 2x2 micro-tile.
// float4 staging, 16B-aligned LDS rows (pad 36), conflict-free inner reads.
// ---------------------------------------------------------------------------

// ---- fused QKV: y[z] = x @ W[z], grid (16, 8, 3)
__global__ __launch_bounds__(256) void qkv_kernel(
    const float* __restrict__ x,
    const float* __restrict__ Wq, const float* __restrict__ Wk,
    const float* __restrict__ Wv, float* __restrict__ y)
{
    __shared__ __align__(16) float As[32][36];
    __shared__ __align__(16) float Bs[32][36];

    const int z = blockIdx.z;
    const float* W = (z == 0) ? Wq : (z == 1) ? Wk : Wv;
    float* C = y + (long)z * (T_ * D_);

    const int tid = threadIdx.x;
    const int tx = tid & 15, ty = tid >> 4;
    const int row0 = blockIdx.y * 32, col0 = blockIdx.x * 32;
    const int r4 = tid >> 3, c4 = tid & 7;

    float acc00 = 0.f, acc01 = 0.f, acc10 = 0.f, acc11 = 0.f;

    for (int k0 = 0; k0 < D_; k0 += 32) {
        *(float4*)&As[r4][c4 * 4] = *(const float4*)(x + (long)(row0 + r4) * D_ + k0 + c4 * 4);
        *(float4*)&Bs[r4][c4 * 4] = *(const float4*)(W + (long)(k0 + r4) * D_ + col0 + c4 * 4);
        __syncthreads();
        #pragma unroll
        for (int kk = 0; kk < 32; ++kk) {
            float a0 = As[ty * 2 + 0][kk];
            float a1 = As[ty * 2 + 1][kk];
            float b0 = Bs[kk][tx * 2 + 0];
            float b1 = Bs[kk][tx * 2 + 1];
            acc00 = fmaf(a0, b0, acc00); acc01 = fmaf(a0, b1, acc01);
            acc10 = fmaf(a1, b0, acc10); acc11 = fmaf(a1, b1, acc11);
        }
        __syncthreads();
    }
    C[(long)(row0 + ty * 2 + 0) * D_ + col0 + tx * 2 + 0] = acc00;
    C[(long)(row0 + ty * 2 + 0) * D_ + col0 + tx * 2 + 1] = acc01;
    C[(long)(row0 + ty * 2 + 1) * D_ + col0 + tx * 2 + 0] = acc10;
    C[(long)(row0 + ty * 2 + 1) * D_ + col0 + tx * 2 + 1] = acc11;
}

// ---- a_i / a_j with coords via K-concat (K = 64 + 64), grid (8, 8, 16)
__global__ __launch_bounds__(256) void aiaj_kernel(
    const float* __restrict__ y, const float* __restrict__ coords,
    const float* __restrict__ W1, const float* __restrict__ b1,
    float* __restrict__ abuf)
{
    __shared__ __align__(16) float As[32][36];
    __shared__ __align__(16) float Bs[32][36];

    const int z = blockIdx.z;
    const int sel = z >> 3, h = z & 7;
    const float* Ay = y + (long)sel * (T_ * D_) + h * HD_;
    float* C = abuf + (long)z * (T_ * HID_);

    const int tid = threadIdx.x;
    const int tx = tid & 15, ty = tid >> 4;
    const int row0 = blockIdx.y * 32, col0 = blockIdx.x * 32;
    const int r4 = tid >> 3, c4 = tid & 7;

    float acc00 = 0.f, acc01 = 0.f, acc10 = 0.f, acc11 = 0.f;

    for (int k0 = 0; k0 < 128; k0 += 32) {
        if (k0 < 64) {
            *(float4*)&As[r4][c4 * 4] =
                *(const float4*)(Ay + (long)(row0 + r4) * D_ + k0 + c4 * 4);
            *(float4*)&Bs[r4][c4 * 4] =
                *(const float4*)(W1 + (long)(sel * 64 + k0 + r4) * HID_ + col0 + c4 * 4);
        } else {
            *(float4*)&As[r4][c4 * 4] =
                *(const float4*)(coords + (long)(row0 + r4) * M_ + (k0 - 64) + c4 * 4);
            *(float4*)&Bs[r4][c4 * 4] =
                *(const float4*)(W1 + (long)(128 + 64 * sel + k0 - 64 + r4) * HID_ + col0 + c4 * 4);
        }
        __syncthreads();
        #pragma unroll
        for (int kk = 0; kk < 32; ++kk) {
            float a0 = As[ty * 2 + 0][kk];
            float a1 = As[ty * 2 + 1][kk];
            float b0 = Bs[kk][tx * 2 + 0];
            float b1 = Bs[kk][tx * 2 + 1];
            acc00 = fmaf(a0, b0, acc00); acc01 = fmaf(a0, b1, acc01);
            acc10 = fmaf(a1, b0, acc10); acc11 = fmaf(a1, b1, acc11);
        }
        __syncthreads();
    }
    const int c0 = col0 + tx * 2, r0 = row0 + ty * 2;
    float bb0 = (sel == 1) ? b1[c0 + 0] : 0.f;
    float bb1 = (sel == 1) ? b1[c0 + 1] : 0.f;
    C[(long)(r0 + 0) * HID_ + c0 + 0] = acc00 + bb0;
    C[(long)(r0 + 0) * HID_ + c0 + 1] = acc01 + bb1;
    C[(long)(r0 + 1) * HID_ + c0 + 0] = acc10 + bb0;
    C[(long)(r0 + 1) * HID_ + c0 + 1] = acc11 + bb1;
}

// ---------------------------------------------------------------------------
// pairwise v5: 32x32 (i,j) tile, feature-split in 4 (64 features per block).
// Raw partial sums to pb[h*4+s][i][j]. Grid (8 jt, 8 it, 32 hs) = 2048 blocks.
// LDS ~17.5 KB -> ~8 blocks/CU.
// ---------------------------------------------------------------------------
#define SILU_ACC(acc, w, aa, bb) \
    { float t_ = (aa) + (bb); \
      float sg_ = __builtin_amdgcn_rcpf(1.f + __expf(-t_)); \
      acc = fmaf((w) * t_, sg_, acc); }

__global__ __launch_bounds__(256) void pairwise_kernel(
    const float* __restrict__ a_i, const float* __restrict__ a_j,
    const float* __restrict__ W2, float* __restrict__ pb)
{
    const int jt = blockIdx.x, it = blockIdx.y, hs = blockIdx.z;
    const int h = hs >> 2, fb = (hs & 3) * 64;
    const int t = threadIdx.x;

    __shared__ __align__(16) float ai_s[32][68];
    __shared__ __align__(16) float aj_s[32][68];
    __shared__ __align__(16) float w2d[64];

    if (t < 64) w2d[t] = W2[(fb + t) * 2 + 0] - W2[(fb + t) * 2 + 1];

    const float* aib = a_i + ((long)h * T_ + it * 32) * HID_ + fb;
    const float* ajb = a_j + ((long)h * T_ + jt * 32) * HID_ + fb;
    #pragma unroll
    for (int l = 0; l < 2; ++l) {
        int idx = t + l * 256;          // float4 id 0..511
        int r = idx >> 4, c4 = idx & 15;
        *(float4*)&ai_s[r][c4 * 4] = *(const float4*)(aib + (long)r * HID_ + c4 * 4);
        *(float4*)&aj_s[r][c4 * 4] = *(const float4*)(ajb + (long)r * HID_ + c4 * 4);
    }
    __syncthreads();

    const int ty = t >> 4, tx = t & 15;
    float s00 = 0.f, s01 = 0.f, s10 = 0.f, s11 = 0.f;

    #pragma unroll 4
    for (int f4 = 0; f4 < 16; ++f4) {
        float4 a0 = *(const float4*)&ai_s[ty][f4 * 4];
        float4 a1 = *(const float4*)&ai_s[ty + 16][f4 * 4];
        float4 c0 = *(const float4*)&aj_s[tx][f4 * 4];
        float4 c1 = *(const float4*)&aj_s[tx + 16][f4 * 4];
        float4 w  = *(const float4*)&w2d[f4 * 4];
        SILU_ACC(s00, w.x, a0.x, c0.x); SILU_ACC(s01, w.x, a0.x, c1.x);
        SILU_ACC(s10, w.x, a1.x, c0.x); SILU_ACC(s11, w.x, a1.x, c1.x);
        SILU_ACC(s00, w.y, a0.y, c0.y); SILU_ACC(s01, w.y, a0.y, c1.y);
        SILU_ACC(s10, w.y, a1.y, c0.y); SILU_ACC(s11, w.y, a1.y, c1.y);
        SILU_ACC(s00, w.z, a0.z, c0.z); SILU_ACC(s01, w.z, a0.z, c1.z);
        SILU_ACC(s10, w.z, a1.z, c0.z); SILU_ACC(s11, w.z, a1.z, c1.z);
        SILU_ACC(s00, w.w, a0.w, c0.w); SILU_ACC(s01, w.w, a0.w, c1.w);
        SILU_ACC(s10, w.w, a1.w, c0.w); SILU_ACC(s11, w.w, a1.w, c1.w);
    }

    const int gi0 = it * 32 + ty, gi1 = gi0 + 16;
    const int gj0 = jt * 32 + tx, gj1 = gj0 + 16;
    float* pbh = pb + (long)hs * (T_ * T_);
    pbh[(long)gi0 * T_ + gj0] = s00;
    pbh[(long)gi0 * T_ + gj1] = s01;
    pbh[(long)gi1 * T_ + gj0] = s10;
    pbh[(long)gi1 * T_ + gj1] = s11;
}

// ---------------------------------------------------------------------------
// attn: one block per row i (512 threads = 8 waves = 8 heads).
// Merge 4 pb partials + b2d -> tanh -> causal softmax -> PV -> o row.
// ---------------------------------------------------------------------------
__global__ __launch_bounds__(512) void attn_kernel(
    const float* __restrict__ pb, const float* __restrict__ yv,
    const float* __restrict__ b2, float* __restrict__ o,
    float* __restrict__ parts)
{
    const int i = blockIdx.x, t = threadIdx.x;
    const int w = t >> 6, lane = t & 63;

    __shared__ float p[8][256];
    __shared__ float psc[8];

    const float b2d = b2[0] - b2[1];

    const float* pb0 = pb + ((long)(4 * w + 0) * T_ + i) * T_;
    const float* pb1 = pb + ((long)(4 * w + 1) * T_ + i) * T_;
    const float* pb2 = pb + ((long)(4 * w + 2) * T_ + i) * T_;
    const float* pb3 = pb + ((long)(4 * w + 3) * T_ + i) * T_;
    float sv[4];
    float mx = -1e30f, wsum = 0.f, asum = 0.f;
    #pragma unroll
    for (int r = 0; r < 4; ++r) {
        int j = lane + r * 64;
        float s = ((pb0[j] + pb1[j]) + (pb2[j] + pb3[j])) + b2d;
        float as = fabsf(s);
        float e = __expf(-as);
        float tv = (1.f - e) * __builtin_amdgcn_rcpf(1.f + e);   // tanh(|s|/2)
        float lk = (s < 0.f) ? -tv : tv;                          // tanh(s/2)
        wsum += lk; asum += fabsf(lk);
        float sc = (j <= i) ? lk * 0.125f : -1e30f;
        sv[r] = sc; mx = fmaxf(mx, sc);
    }
    #pragma unroll
    for (int off = 32; off > 0; off >>= 1) mx = fmaxf(mx, __shfl_xor(mx, off));
    float sum = 0.f;
    #pragma unroll
    for (int r = 0; r < 4; ++r) {
        int j = lane + r * 64;
        float e = (j <= i) ? __expf(sv[r] - mx) : 0.f;
        p[w][j] = e; sum += e;
    }
    #pragma unroll
    for (int off = 32; off > 0; off >>= 1) {
        sum  += __shfl_xor(sum, off);
        wsum += __shfl_xor(wsum, off);
        asum += __shfl_xor(asum, off);
    }
    if (lane == 0) {
        psc[w] = __builtin_amdgcn_rcpf(sum);
        parts[((long)i * 8 + w) * 2 + 0] = wsum;
        parts[((long)i * 8 + w) * 2 + 1] = asum;
    }
    __syncthreads();

    // PV: thread t owns output column t (head w, d = lane); 8-deep ILP
    const float pinv = psc[w];
    const float* vb = yv + t;
    float a0 = 0.f, a1 = 0.f, a2 = 0.f, a3 = 0.f;
    float a4 = 0.f, a5 = 0.f, a6 = 0.f, a7 = 0.f;
    int j = 0;
    for (; j + 7 <= i; j += 8) {
        a0 = fmaf(p[w][j + 0], vb[(long)(j + 0) * D_], a0);
        a1 = fmaf(p[w][j + 1], vb[(long)(j + 1) * D_], a1);
        a2 = fmaf(p[w][j + 2], vb[(long)(j + 2) * D_], a2);
        a3 = fmaf(p[w][j + 3], vb[(long)(j + 3) * D_], a3);
        a4 = fmaf(p[w][j + 4], vb[(long)(j + 4) * D_], a4);
        a5 = fmaf(p[w][j + 5], vb[(long)(j + 5) * D_], a5);
        a6 = fmaf(p[w][j + 6], vb[(long)(j + 6) * D_], a6);
        a7 = fmaf(p[w][j + 7], vb[(long)(j + 7) * D_], a7);
    }
    for (; j <= i; ++j) a0 = fmaf(p[w][j], vb[(long)j * D_], a0);
    o[(long)i * D_ + t] = (((a0 + a1) + (a2 + a3)) + ((a4 + a5) + (a6 + a7))) * pinv;
}

// ---------------------------------------------------------------------------
// Epilogue, K-split x2 for occupancy.
// epA: h[z] = o @ W3[z-half]                       grid (16, 8, 2)
// epB: g2[z] = silu(h0+h1+b3) @ W4[z-half]         grid (16, 8, 2)
// epC: out = (g20+g21+b4) @ Wo  (+ tail reduce)    grid (16, 8)
// ---------------------------------------------------------------------------
__global__ __launch_bounds__(256) void epA_kernel(
    const float* __restrict__ o, const float* __restrict__ W3,
    float* __restrict__ hbuf)
{
    __shared__ __align__(16) float As[32][36];
    __shared__ __align__(16) float Bs[32][36];

    const int z = blockIdx.z;
    float* C = hbuf + (long)z * (T_ * D_);
    const int tid = threadIdx.x;
    const int tx = tid & 15, ty = tid >> 4;
    const int row0 = blockIdx.y * 32, col0 = blockIdx.x * 32;
    const int r4 = tid >> 3, c4 = tid & 7;

    float acc00 = 0.f, acc01 = 0.f, acc10 = 0.f, acc11 = 0.f;

    for (int k0 = z * 256; k0 < z * 256 + 256; k0 += 32) {
        *(float4*)&As[r4][c4 * 4] = *(const float4*)(o + (long)(row0 + r4) * D_ + k0 + c4 * 4);
        *(float4*)&Bs[r4][c4 * 4] = *(const float4*)(W3 + (long)(k0 + r4) * D_ + col0 + c4 * 4);
        __syncthreads();
        #pragma unroll
        for (int kk = 0; kk < 32; ++kk) {
            float a0 = As[ty * 2 + 0][kk];
            float a1 = As[ty * 2 + 1][kk];
            float b0 = Bs[kk][tx * 2 + 0];
            float b1 = Bs[kk][tx * 2 + 1];
            acc00 = fmaf(a0, b0, acc00); acc01 = fmaf(a0, b1, acc01);
            acc10 = fmaf(a1, b0, acc10); acc11 = fmaf(a1, b1, acc11);
        }
        __syncthreads();
    }
    C[(long)(row0 + ty * 2 + 0) * D_ + col0 + tx * 2 + 0] = acc00;
    C[(long)(row0 + ty * 2 + 0) * D_ + col0 + tx * 2 + 1] = acc01;
    C[(long)(row0 + ty * 2 + 1) * D_ + col0 + tx * 2 + 0] = acc10;
    C[(long)(row0 + ty * 2 + 1) * D_ + col0 + tx * 2 + 1] = acc11;
}

__global__ __launch_bounds__(256) void epB_kernel(
    const float* __restrict__ hbuf, const float* __restrict__ b3,
    const float* __restrict__ W4, float* __restrict__ gbuf)
{
    __shared__ __align__(16) float As[32][36];
    __shared__ __align__(16) float Bs[32][36];

    const int z = blockIdx.z;
    const float* h0 = hbuf;
    const float* h1 = hbuf + (T_ * D_);
    float* C = gbuf + (long)z * (T_ * D_);
    const int tid = threadIdx.x;
    const int tx = tid & 15, ty = tid >> 4;
    const int row0 = blockIdx.y * 32, col0 = blockIdx.x * 32;
    const int r4 = tid >> 3, c4 = tid & 7;

    float acc00 = 0.f, acc01 = 0.f, acc10 = 0.f, acc11 = 0.f;

    for (int k0 = z * 256; k0 < z * 256 + 256; k0 += 32) {
        {
            long off = (long)(row0 + r4) * D_ + k0 + c4 * 4;
            float4 v0 = *(const float4*)(h0 + off);
            float4 v1 = *(const float4*)(h1 + off);
            float4 bb = *(const float4*)(b3 + k0 + c4 * 4);
            float4 g;
            g.x = v0.x + v1.x + bb.x; g.y = v0.y + v1.y + bb.y;
            g.z = v0.z + v1.z + bb.z; g.w = v0.w + v1.w + bb.w;
            g.x = g.x * __builtin_amdgcn_rcpf(1.f + __expf(-g.x));
            g.y = g.y * __builtin_amdgcn_rcpf(1.f + __expf(-g.y));
            g.z = g.z * __builtin_amdgcn_rcpf(1.f + __expf(-g.z));
            g.w = g.w * __builtin_amdgcn_rcpf(1.f + __expf(-g.w));
            *(float4*)&As[r4][c4 * 4] = g;
        }
        *(float4*)&Bs[r4][c4 * 4] = *(const float4*)(W4 + (long)(k0 + r4) * D_ + col0 + c4 * 4);
        __syncthreads();
        #pragma unroll
        for (int kk = 0; kk < 32; ++kk) {
            float a0 = As[ty * 2 + 0][kk];
            float a1 = As[ty * 2 + 1][kk];
            float b0 = Bs[kk][tx * 2 + 0];
            float b1 = Bs[kk][tx * 2 + 1];
            acc00 = fmaf(a0, b0, acc00); acc01 = fmaf(a0, b1, acc01);
            acc10 = fmaf(a1, b0, acc10); acc11 = fmaf(a1, b1, acc11);
        }
        __syncthreads();
    }
    C[(long)(row0 + ty * 2 + 0) * D_ + col0 + tx * 2 + 0] = acc00;
    C[(long)(row0 + ty * 2 + 0) * D_ + col0 + tx * 2 + 1] = acc01;
    C[(long)(row0 + ty * 2 + 1) * D_ + col0 + tx * 2 + 0] = acc10;
    C[(long)(row0 + ty * 2 + 1) * D_ + col0 + tx * 2 + 1] = acc11;
}

__global__ __launch_bounds__(256) void epC_kernel(
    const float* __restrict__ gbuf, const float* __restrict__ b4,
    const float* __restrict__ Wo, float* __restrict__ out,
    const float* __restrict__ parts, float* __restrict__ tailo)
{
    __shared__ __align__(16) float As[32][36];
    __shared__ __align__(16) float Bs[32][36];

    const float* g0 = gbuf;
    const float* g1 = gbuf + (T_ * D_);
    const int tid = threadIdx.x;
    const int tx = tid & 15, ty = tid >> 4;
    const int row0 = blockIdx.y * 32, col0 = blockIdx.x * 32;
    const int r4 = tid >> 3, c4 = tid & 7;

    float acc00 = 0.f, acc01 = 0.f, acc10 = 0.f, acc11 = 0.f;

    for (int k0 = 0; k0 < D_; k0 += 32) {
        {
            long off = (long)(row0 + r4) * D_ + k0 + c4 * 4;
            float4 v0 = *(const float4*)(g0 + off);
            float4 v1 = *(const float4*)(g1 + off);
            float4 bb = *(const float4*)(b4 + k0 + c4 * 4);
            float4 g;
            g.x = v0.x + v1.x + bb.x; g.y = v0.y + v1.y + bb.y;
            g.z = v0.z + v1.z + bb.z; g.w = v0.w + v1.w + bb.w;
            *(float4*)&As[r4][c4 * 4] = g;
        }
        *(float4*)&Bs[r4][c4 * 4] = *(const float4*)(Wo + (long)(k0 + r4) * D_ + col0 + c4 * 4);
        __syncthreads();
        #pragma unroll
        for (int kk = 0; kk < 32; ++kk) {
            float a0 = As[ty * 2 + 0][kk];
            float a1 = As[ty * 2 + 1][kk];
            float b0 = Bs[kk][tx * 2 + 0];
            float b1 = Bs[kk][tx * 2 + 1];
            acc00 = fmaf(a0, b0, acc00); acc01 = fmaf(a0, b1, acc01);
            acc10 = fmaf(a1, b0, acc10); acc11 = fmaf(a1, b1, acc11);
        }
        __syncthreads();
    }
    out[(long)(row0 + ty * 2 + 0) * D_ + col0 + tx * 2 + 0] = acc00;
    out[(long)(row0 + ty * 2 + 0) * D_ + col0 + tx * 2 + 1] = acc01;
    out[(long)(row0 + ty * 2 + 1) * D_ + col0 + tx * 2 + 0] = acc10;
    out[(long)(row0 + ty * 2 + 1) * D_ + col0 + tx * 2 + 1] = acc11;

    // tail reduce folded into block (0,0): writhe[8] + linking_mean
    if (blockIdx.x == 0 && blockIdx.y == 0 && tid < 64) {
        const int lane = tid;
        if (lane < 8) {
            float wsum = 0.f;
            for (int i = 0; i < 256; ++i) wsum += parts[((long)i * 8 + lane) * 2 + 0];
            tailo[lane] = wsum;
        }
        float a = 0.f;
        for (int idx = lane; idx < 2048; idx += 64) a += parts[(long)idx * 2 + 1];
        #pragma unroll
        for (int off = 32; off > 0; off >>= 1) a += __shfl_xor(a, off);
        if (lane == 0) tailo[8] = a / (float)(H_ * T_ * T_);
    }
}

// ---------------------------------------------------------------------------
extern "C" void kernel_launch(void* const* d_in, const int* in_sizes, int n_in,
                              void* d_out, int out_size, void* d_ws, size_t ws_size,
                              hipStream_t stream)
{
    const float* x      = (const float*)d_in[0];
    const float* coords = (const float*)d_in[1];
    const float* Wq     = (const float*)d_in[2];
    const float* Wk     = (const float*)d_in[3];
    const float* Wv     = (const float*)d_in[4];
    const float* Wo     = (const float*)d_in[5];
    const float* W1     = (const float*)d_in[6];
    const float* b1     = (const float*)d_in[7];
    const float* W2     = (const float*)d_in[8];
    const float* b2     = (const float*)d_in[9];
    const float* W3     = (const float*)d_in[10];
    const float* b3     = (const float*)d_in[11];
    const float* W4     = (const float*)d_in[12];
    const float* b4     = (const float*)d_in[13];
    float* out = (float*)d_out;

    float* ws = (float*)d_ws;
    float* y     = ws;                    // 3 * 256*512      = 393216
    float* ai    = ws + 393216;           // abuf: ai [0..7], aj [8..15]
    float* aj    = ws + 917504;
    float* pb    = ws + 1441792;          // 32*256*256       = 2097152
    float* o     = ws + 3538944;          // 256*512
    float* hb    = ws + 3670016;          // 2 * 256*512
    float* gb    = ws + 3932160;          // 2 * 256*512
    float* parts = ws + 4194304;          // 256*8*2

    // 1) q,k,v projections
    qkv_kernel<<<dim3(16, 8, 3), dim3(256), 0, stream>>>(x, Wq, Wk, Wv, y);

    // 2) a_i / a_j (coords K-concat, b1 folded)
    aiaj_kernel<<<dim3(8, 8, 16), dim3(256), 0, stream>>>(y, coords, W1, b1, ai);

    // 3) pairwise silu-MLP raw partials (feature-split 4x)
    pairwise_kernel<<<dim3(8, 8, 32), dim3(256), 0, stream>>>(ai, aj, W2, pb);

    // 4) tanh -> causal softmax -> PV (+ row partials)
    attn_kernel<<<dim3(T_), dim3(512), 0, stream>>>(pb, y + 2 * (T_ * D_), b2, o, parts);

    // 5) epilogue, K-split x2
    epA_kernel<<<dim3(16, 8, 2), dim3(256), 0, stream>>>(o, W3, hb);
    epB_kernel<<<dim3(16, 8, 2), dim3(256), 0, stream>>>(hb, b3, W4, gb);
    epC_kernel<<<dim3(16, 8), dim3(256), 0, stream>>>(gb, b4, Wo, out, parts, out + 131072);
}